// Round 1
// baseline (2281.930 us; speedup 1.0000x reference)
//
#include <hip/hip_runtime.h>
#include <cstdint>

// ---------------- helpers ----------------
__device__ inline void atomAddF(float* p, float v) { unsafeAtomicAdd(p, v); }

// ---------------- small kernels ----------------
__global__ void zero_kernel(float* __restrict__ p, int n) {
    int i = blockIdx.x * 256 + threadIdx.x;
    if (i < n) p[i] = 0.f;
}

// Classify gene_paths_mask storage: 0 = int32 words (0/1), 1 = bool bytes, 2 = float32 (0/1.0)
__global__ void detect_mask_kernel(const unsigned char* __restrict__ m, int nbytes, int* __restrict__ flag) {
    __shared__ int isByte, isFloat;
    if (threadIdx.x == 0) { isByte = 0; isFloat = 0; }
    __syncthreads();
    const unsigned* w = (const unsigned*)m;
    for (int i = threadIdx.x; i < nbytes / 4; i += blockDim.x) {
        unsigned v = w[i];
        if (v == 0u || v == 1u) continue;
        if (v == 0x3f800000u) isFloat = 1; else isByte = 1;
    }
    __syncthreads();
    if (threadIdx.x == 0) *flag = isFloat ? 2 : (isByte ? 1 : 0);
}

__global__ void deg_kernel(const int* __restrict__ dst, const float* __restrict__ ew,
                           float* __restrict__ deg, int E) {
    int e = blockIdx.x * 256 + threadIdx.x;
    if (e < E) atomAddF(&deg[dst[e]], ew[e]);
}

__global__ void norm_kernel(float* __restrict__ deg, int P) {
    int i = blockIdx.x * 256 + threadIdx.x;
    if (i < P) deg[i] = rsqrtf(deg[i] + 1.0f);
}

// out[i,f] (=|+=) H[i,f]*norm[i]^2 + bias[f]
__global__ void self_term_kernel(const float* __restrict__ H, const float* __restrict__ norm,
                                 const float* __restrict__ bias, float* __restrict__ out,
                                 int P, int F, int accumulate) {
    long long idx = (long long)blockIdx.x * 256 + threadIdx.x;
    if (idx >= (long long)P * F) return;
    int i = (int)(idx / F), f = (int)(idx % F);
    float n = norm[i];
    float v = H[idx] * n * n + bias[f];
    if (accumulate) out[idx] += v; else out[idx] = v;
}

// one wave (64 lanes) per edge
__global__ __launch_bounds__(256) void edge_scatter_kernel(
    const float* __restrict__ H, float* __restrict__ out,
    const int* __restrict__ src, const int* __restrict__ dst,
    const float* __restrict__ ew, const float* __restrict__ norm, int E, int F) {
    int gid = blockIdx.x * 256 + threadIdx.x;
    int e = gid >> 6, lane = gid & 63;
    if (e >= E) return;
    int si = src[e], di = dst[e];
    float c = ew[e] * norm[si] * norm[di];
    const float* hrow = H + (size_t)si * F;
    float* orow = out + (size_t)di * F;
    for (int f = lane; f < F; f += 64) atomAddF(&orow[f], hrow[f] * c);
}

__global__ void relu_kernel(float* __restrict__ p, int n) {
    int i = blockIdx.x * 256 + threadIdx.x;
    if (i < n) p[i] = fmaxf(p[i], 0.f);
}

// ---------------- tiled fp32 GEMM: C = A[MxK] @ B[KxN] (+bias) (+relu) ----------------
#define BM 64
#define BN 64
#define BKK 16
__global__ __launch_bounds__(256) void sgemm_kernel(
    const float* __restrict__ A, const float* __restrict__ B, float* __restrict__ C,
    const float* __restrict__ bias, int M, int N, int K, int relu) {
    __shared__ float As[BKK][BM + 4];
    __shared__ float Bs[BKK][BN + 4];
    int t = threadIdx.x;
    int tx = t & 15, ty = t >> 4;
    int row0 = blockIdx.y * BM, col0 = blockIdx.x * BN;
    float acc[4][4] = {};
    for (int kt = 0; kt < K; kt += BKK) {
#pragma unroll
        for (int i = 0; i < 4; ++i) {
            int e = t + i * 256;
            int r = e >> 4, c = e & 15;
            int gr = row0 + r, gc = kt + c;
            As[c][r] = (gr < M && gc < K) ? A[(size_t)gr * K + gc] : 0.f;
        }
#pragma unroll
        for (int i = 0; i < 4; ++i) {
            int e = t + i * 256;
            int r = e >> 6, c = e & 63;
            int gr = kt + r, gc = col0 + c;
            Bs[r][c] = (gr < K && gc < N) ? B[(size_t)gr * N + gc] : 0.f;
        }
        __syncthreads();
#pragma unroll
        for (int k = 0; k < BKK; ++k) {
            float4 av = *reinterpret_cast<const float4*>(&As[k][ty * 4]);
            float4 bv = *reinterpret_cast<const float4*>(&Bs[k][tx * 4]);
            float a[4] = {av.x, av.y, av.z, av.w};
            float b[4] = {bv.x, bv.y, bv.z, bv.w};
#pragma unroll
            for (int i = 0; i < 4; ++i)
#pragma unroll
                for (int j = 0; j < 4; ++j) acc[i][j] += a[i] * b[j];
        }
        __syncthreads();
    }
#pragma unroll
    for (int i = 0; i < 4; ++i) {
        int r = row0 + ty * 4 + i;
        if (r >= M) continue;
#pragma unroll
        for (int j = 0; j < 4; ++j) {
            int c = col0 + tx * 4 + j;
            if (c >= N) continue;
            float v = acc[i][j] + (bias ? bias[c] : 0.f);
            if (relu) v = fmaxf(v, 0.f);
            C[(size_t)r * N + c] = v;
        }
    }
}

// ---------------- gene pathway gather: one wave per gene ----------------
// feat[b, r*64 + d] = sum over masked paths p with root r of s[path, d]
__global__ __launch_bounds__(64) void gene_feat_kernel(
    const float* __restrict__ S, const int* __restrict__ ids,
    const int* __restrict__ gene_paths, const void* __restrict__ mask,
    const int* __restrict__ root, float* __restrict__ feat, const int* __restrict__ flag) {
    __shared__ float lds[28 * 64];
    int lane = threadIdx.x;
#pragma unroll
    for (int i = 0; i < 28; ++i) lds[i * 64 + lane] = 0.f;
    int gene = ids[blockIdx.x];
    int fl = *flag;
    const unsigned char* mb = (const unsigned char*)mask;
    const int* mi = (const int*)mask;
    const float* mf = (const float*)mask;
    for (int p = 0; p < 32; ++p) {
        int idx = gene * 32 + p;
        int m = (fl == 0) ? mi[idx] : (fl == 1) ? (int)mb[idx] : (mf[idx] != 0.f);
        if (!m) continue;
        int path = gene_paths[idx];
        int r = root[path];
        lds[r * 64 + lane] += S[(size_t)path * 64 + lane];
    }
    float* frow = feat + (size_t)blockIdx.x * 1792;
#pragma unroll
    for (int i = 0; i < 28; ++i) frow[i * 64 + lane] = lds[i * 64 + lane];
}

// ---------------- batchnorm ----------------
__global__ __launch_bounds__(256) void bn_stats_kernel(const float* __restrict__ X, int Mrows, int C,
                                                       float* __restrict__ mean, float* __restrict__ rstd) {
    int c = blockIdx.x;
    float s = 0.f, s2 = 0.f;
    for (int r = threadIdx.x; r < Mrows; r += 256) {
        float v = X[(size_t)r * C + c];
        s += v; s2 += v * v;
    }
    for (int off = 32; off; off >>= 1) { s += __shfl_down(s, off); s2 += __shfl_down(s2, off); }
    __shared__ float sh[2][4];
    int lane = threadIdx.x & 63, wv = threadIdx.x >> 6;
    if (lane == 0) { sh[0][wv] = s; sh[1][wv] = s2; }
    __syncthreads();
    if (threadIdx.x == 0) {
        float ts = 0.f, ts2 = 0.f;
        for (int i = 0; i < 4; ++i) { ts += sh[0][i]; ts2 += sh[1][i]; }
        float mu = ts / Mrows;
        float var = ts2 / Mrows - mu * mu;
        mean[c] = mu;
        rstd[c] = rsqrtf(var + 1e-5f);
    }
}

__global__ void bn_apply_kernel(const float* __restrict__ X, float* __restrict__ Y,
                                int Mrows, int C, int ldY, int colOff,
                                const float* __restrict__ g, const float* __restrict__ b,
                                const float* __restrict__ mean, const float* __restrict__ rstd, int relu) {
    long long idx = (long long)blockIdx.x * 256 + threadIdx.x;
    if (idx >= (long long)Mrows * C) return;
    int r = (int)(idx / C), c = (int)(idx % C);
    float v = (X[idx] - mean[c]) * rstd[c] * g[c] + b[c];
    if (relu) v = fmaxf(v, 0.f);
    Y[(size_t)r * ldY + colOff + c] = v;
}

// ---------------- final N=1 GEMV: one wave per row ----------------
__global__ __launch_bounds__(256) void gemv_out_kernel(const float* __restrict__ X, const float* __restrict__ w,
                                                       const float* __restrict__ b, float* __restrict__ out,
                                                       int M, int K) {
    int gid = blockIdx.x * 256 + threadIdx.x;
    int row = gid >> 6, lane = gid & 63;
    if (row >= M) return;
    float sum = 0.f;
    for (int k = lane; k < K; k += 64) sum += X[(size_t)row * K + k] * w[k];
    for (int off = 32; off; off >>= 1) sum += __shfl_down(sum, off);
    if (lane == 0) out[row] = sum + b[0];
}

// ---------------- launch ----------------
extern "C" void kernel_launch(void* const* d_in, const int* in_sizes, int n_in,
                              void* d_out, int out_size, void* d_ws, size_t ws_size,
                              hipStream_t stream) {
    const float* x1 = (const float*)d_in[0];
    const float* x2 = (const float*)d_in[1];
    const int* esrc = (const int*)d_in[2];
    const int* edst = (const int*)d_in[3];
    const float* ew = (const float*)d_in[4];
    const float* g_w1[2] = {(const float*)d_in[5], (const float*)d_in[9]};
    const float* g_b1[2] = {(const float*)d_in[6], (const float*)d_in[10]};
    const float* g_w2[2] = {(const float*)d_in[7], (const float*)d_in[11]};
    const float* g_b2[2] = {(const float*)d_in[8], (const float*)d_in[12]};
    const float* pl1_w = (const float*)d_in[13];
    const float* pl1_b = (const float*)d_in[14];
    const float* bn1_g = (const float*)d_in[15];
    const float* bn1_b = (const float*)d_in[16];
    const float* pl2_w = (const float*)d_in[17];
    const float* pl2_b = (const float*)d_in[18];
    const float* bn2_g = (const float*)d_in[19];
    const float* bn2_b = (const float*)d_in[20];
    const float* fc_w = (const float*)d_in[21];
    const float* fc_b = (const float*)d_in[22];
    const float* fc1_w = (const float*)d_in[23];
    const float* fc1_b = (const float*)d_in[24];
    const float* fc2_w = (const float*)d_in[25];
    const float* fc2_b = (const float*)d_in[26];
    const int* root = (const int*)d_in[27];
    const int* gene_paths = (const int*)d_in[28];
    const void* gmask = d_in[29];
    const int* head = (const int*)d_in[30];
    const int* tail = (const int*)d_in[31];

    const int P = in_sizes[27];      // 30000
    const int E = in_sizes[2];       // 480000
    const int B = in_sizes[30];      // 4096
    const int IN = 394, H = 256, OUT = 64, GD = 128;

    char* ws = (char*)d_ws;
    size_t off = 0;
    auto alloc = [&](size_t bytes) -> char* {
        char* p = ws + off;
        off = (off + bytes + 255) & ~(size_t)255;
        return p;
    };
    int* flag = (int*)alloc(256);
    float* norm = (float*)alloc((size_t)P * 4);
    float* bufA = (float*)alloc((size_t)P * H * 4);   // x@W1, then h@W2, then feat
    float* bufB = (float*)alloc((size_t)P * H * 4);   // agg1/h1, then MLP scratch
    float* s = (float*)alloc((size_t)P * OUT * 4);
    float* bn_mean = (float*)alloc(256 * 4);
    float* bn_rstd = (float*)alloc(256 * 4);
    (void)ws_size; (void)n_in;

    float* feat = bufA;                     // [B,1792] after GCN done
    float* z1 = bufB;                       // [B,256]
    float* z2 = bufB + 1310720;             // [B,128]
    float* fuse_cat = bufB + 2097152;       // [B,256] persists both sides
    float* t1 = bufB + 4194304;             // [B,256]
    float* t2 = bufB + 5242880;             // [B,128]

    auto gemm = [&](const float* A, const float* Bm, float* C, const float* bias,
                    int M, int N, int K, int relu) {
        dim3 grid((N + BN - 1) / BN, (M + BM - 1) / BM);
        sgemm_kernel<<<grid, 256, 0, stream>>>(A, Bm, C, bias, M, N, K, relu);
    };

    // mask storage classification
    detect_mask_kernel<<<1, 256, 0, stream>>>((const unsigned char*)gmask, 4096, flag);

    // degree -> norm
    zero_kernel<<<(P + 255) / 256, 256, 0, stream>>>(norm, P);
    deg_kernel<<<(E + 255) / 256, 256, 0, stream>>>(edst, ew, norm, E);
    norm_kernel<<<(P + 255) / 256, 256, 0, stream>>>(norm, P);

    // two GCN stacks, summed into s
    for (int g = 0; g < 2; ++g) {
        const float* xg = g ? x2 : x1;
        gemm(xg, g_w1[g], bufA, nullptr, P, H, IN, 0);                       // h = x@W1
        self_term_kernel<<<(P * H + 255) / 256, 256, 0, stream>>>(bufA, norm, g_b1[g], bufB, P, H, 0);
        edge_scatter_kernel<<<(E * 64 + 255) / 256, 256, 0, stream>>>(bufA, bufB, esrc, edst, ew, norm, E, H);
        relu_kernel<<<(P * H + 255) / 256, 256, 0, stream>>>(bufB, P * H);   // h1 = relu(conv1)
        gemm(bufB, g_w2[g], bufA, nullptr, P, OUT, H, 0);                    // h2 = h1@W2
        self_term_kernel<<<(P * OUT + 255) / 256, 256, 0, stream>>>(bufA, norm, g_b2[g], s, P, OUT, g);
        edge_scatter_kernel<<<(E * 64 + 255) / 256, 256, 0, stream>>>(bufA, s, esrc, edst, ew, norm, E, OUT);
    }

    // head / tail fuse paths
    const int* ids[2] = {head, tail};
    for (int side = 0; side < 2; ++side) {
        gene_feat_kernel<<<B, 64, 0, stream>>>(s, ids[side], gene_paths, gmask, root, feat, flag);
        gemm(feat, pl1_w, z1, pl1_b, B, 256, 1792, 0);
        bn_stats_kernel<<<256, 256, 0, stream>>>(z1, B, 256, bn_mean, bn_rstd);
        bn_apply_kernel<<<(B * 256 + 255) / 256, 256, 0, stream>>>(z1, z1, B, 256, 256, 0,
                                                                   bn1_g, bn1_b, bn_mean, bn_rstd, 1);
        gemm(z1, pl2_w, z2, pl2_b, B, GD, 256, 0);
        bn_stats_kernel<<<GD, 256, 0, stream>>>(z2, B, GD, bn_mean, bn_rstd);
        bn_apply_kernel<<<(B * GD + 255) / 256, 256, 0, stream>>>(z2, fuse_cat, B, GD, 2 * GD, side * GD,
                                                                  bn2_g, bn2_b, bn_mean, bn_rstd, 0);
    }

    // final MLP
    gemm(fuse_cat, fc_w, t1, fc_b, B, 256, 256, 1);
    gemm(t1, fc1_w, t2, fc1_b, B, 128, 256, 1);   // store relu(fc1 out) — only consumer is fc2
    gemv_out_kernel<<<(B * 64 + 255) / 256, 256, 0, stream>>>(t2, fc2_w, fc2_b, (float*)d_out, B, 128);
}

// Round 2
// 734.236 us; speedup vs baseline: 3.1079x; 3.1079x over previous
//
#include <hip/hip_runtime.h>
#include <cstdint>

typedef __attribute__((ext_vector_type(4))) float f32x4;
typedef __attribute__((ext_vector_type(8))) short s16x8;

__device__ inline unsigned short f2bf(float f) {
    unsigned u = __float_as_uint(f);
    unsigned r = (u + 0x7FFFu + ((u >> 16) & 1u)) >> 16;
    return (unsigned short)r;
}
__device__ inline float b2f(unsigned short h) {
    return __uint_as_float(((unsigned)h) << 16);
}

// ---------------- utility ----------------
__global__ void zero_f_kernel(float* __restrict__ p, int n) {
    int i = blockIdx.x * 256 + threadIdx.x;
    if (i < n) p[i] = 0.f;
}
__global__ void zero_i_kernel(int* __restrict__ p, int n) {
    int i = blockIdx.x * 256 + threadIdx.x;
    if (i < n) p[i] = 0;
}

// Classify gene_paths_mask storage: 0 = int32 words (0/1), 1 = bool bytes, 2 = float32 (0/1.0)
__global__ void detect_mask_kernel(const unsigned char* __restrict__ m, int nbytes, int* __restrict__ flag) {
    __shared__ int isByte, isFloat;
    if (threadIdx.x == 0) { isByte = 0; isFloat = 0; }
    __syncthreads();
    const unsigned* w = (const unsigned*)m;
    for (int i = threadIdx.x; i < nbytes / 4; i += blockDim.x) {
        unsigned v = w[i];
        if (v == 0u || v == 1u) continue;
        if (v == 0x3f800000u) isFloat = 1; else isByte = 1;
    }
    __syncthreads();
    if (threadIdx.x == 0) *flag = isFloat ? 2 : (isByte ? 1 : 0);
}

// ---------------- CSR build ----------------
__global__ void deg_cnt_kernel(const int* __restrict__ dst, const float* __restrict__ ew,
                               float* __restrict__ degw, int* __restrict__ cnt, int E) {
    int e = blockIdx.x * 256 + threadIdx.x;
    if (e >= E) return;
    int d = dst[e];
    unsafeAtomicAdd(&degw[d], ew[e]);
    atomicAdd(&cnt[d], 1);
}

__global__ void norm_kernel(float* __restrict__ degw, int P) {
    int i = blockIdx.x * 256 + threadIdx.x;
    if (i < P) degw[i] = rsqrtf(degw[i] + 1.0f);
}

// single-block exclusive scan: rowstart[0]=0, rowstart[i+1]=sum(cnt[0..i])
__global__ __launch_bounds__(1024) void scan_kernel(const int* __restrict__ cnt,
                                                    int* __restrict__ rowstart, int P) {
    __shared__ int sh[1024];
    __shared__ int carry;
    int t = threadIdx.x;
    if (t == 0) { carry = 0; rowstart[0] = 0; }
    __syncthreads();
    for (int base = 0; base < P; base += 1024) {
        int v = (base + t < P) ? cnt[base + t] : 0;
        sh[t] = v;
        __syncthreads();
        for (int off = 1; off < 1024; off <<= 1) {
            int x = (t >= off) ? sh[t - off] : 0;
            __syncthreads();
            sh[t] += x;
            __syncthreads();
        }
        int c = carry;
        int total = sh[1023];
        __syncthreads();
        if (base + t < P) rowstart[base + t + 1] = c + sh[t];
        if (t == 0) carry = c + total;
        __syncthreads();
    }
}

__global__ void fill_kernel(const int* __restrict__ src, const int* __restrict__ dst,
                            const float* __restrict__ ew, const float* __restrict__ norm,
                            const int* __restrict__ rowstart, int* __restrict__ fill,
                            int* __restrict__ csrc, float* __restrict__ coef, int E) {
    int e = blockIdx.x * 256 + threadIdx.x;
    if (e >= E) return;
    int d = dst[e], sI = src[e];
    int pos = rowstart[d] + atomicAdd(&fill[d], 1);
    csrc[pos] = sI;
    coef[pos] = ew[e] * norm[sI] * norm[d];
}

// ---------------- fused GCN aggregation (CSR gather) ----------------
// out[i,f] = relu( H[i,f]*norm[i]^2 + bias[f] + sum_e H[src,f]*coef )  , F=256, bf16 in/out
__global__ __launch_bounds__(256) void conv1_agg_kernel(
    const unsigned short* __restrict__ H, const float* __restrict__ norm,
    const int* __restrict__ rowstart, const int* __restrict__ csrc, const float* __restrict__ coef,
    const float* __restrict__ bias, unsigned short* __restrict__ out, int P) {
    int node = blockIdx.x;
    int f = threadIdx.x;
    float nn = norm[node];
    float acc = b2f(H[(size_t)node * 256 + f]) * nn * nn;
    int s0 = rowstart[node], s1 = rowstart[node + 1];
    for (int p = s0; p < s1; ++p) {
        int sI = csrc[p];
        float c = coef[p];
        acc += b2f(H[(size_t)sI * 256 + f]) * c;
    }
    acc += bias[f];
    out[(size_t)node * 256 + f] = f2bf(fmaxf(acc, 0.f));
}

// F=64, wave per node, fp32 out with optional accumulate
__global__ __launch_bounds__(256) void conv2_agg_kernel(
    const unsigned short* __restrict__ H, const float* __restrict__ norm,
    const int* __restrict__ rowstart, const int* __restrict__ csrc, const float* __restrict__ coef,
    const float* __restrict__ bias, float* __restrict__ s, int P, int add) {
    int node = blockIdx.x * 4 + (threadIdx.x >> 6);
    int f = threadIdx.x & 63;
    if (node >= P) return;
    float nn = norm[node];
    float acc = b2f(H[(size_t)node * 64 + f]) * nn * nn;
    int s0 = rowstart[node], s1 = rowstart[node + 1];
    for (int p = s0; p < s1; ++p) {
        acc += b2f(H[(size_t)csrc[p] * 64 + f]) * coef[p];
    }
    float v = acc + bias[f];
    size_t o = (size_t)node * 64 + f;
    if (add) s[o] += v; else s[o] = v;
}

// ---------------- transpose + bf16 convert: in[K][N] fp32 -> out[N][Kp] bf16 (zero pad) ----------------
__global__ void transpose_bf16_kernel(const float* __restrict__ in, unsigned short* __restrict__ out,
                                      int K, int N, int Kp) {
    int idx = blockIdx.x * 256 + threadIdx.x;
    if (idx >= N * Kp) return;
    int n = idx / Kp, k = idx % Kp;
    out[idx] = (k < K) ? f2bf(in[(size_t)k * N + n]) : (unsigned short)0;
}

// ---------------- bf16 MFMA GEMM ----------------
// C[M][N] = A[M][K] * Bt[N][K]^T ; A fp32 (converted in staging) or bf16; Bt bf16 pre-transposed.
// Kp = padded K (loop bound, Bt row stride); Kreal = A's valid K; lda = A row stride.
template<int BM, int BN, int WM, int WN, bool ABF16>
__global__ __launch_bounds__(256) void mfma_gemm_kernel(
    const void* __restrict__ Av, const unsigned short* __restrict__ Bt,
    const float* __restrict__ bias,
    float* __restrict__ Cf, unsigned short* __restrict__ Cb,
    int M, int N, int Kreal, int Kp, int lda, int ldc, int relu) {
    constexpr int BK = 32, LDK = BK + 8;
    __shared__ __align__(16) unsigned short As[BM * LDK];
    __shared__ __align__(16) unsigned short Bs[BN * LDK];
    const int t = threadIdx.x;
    const int lane = t & 63, wid = t >> 6;
    constexpr int NWC = BN / WN;
    const int wr = wid / NWC, wc = wid % NWC;
    constexpr int MR = WM / 16, NR = WN / 16;
    const int row0 = blockIdx.y * BM, col0 = blockIdx.x * BN;
    f32x4 acc[MR][NR] = {};
    const int r16 = lane & 15, kb = (lane >> 4) * 8;

    for (int kt = 0; kt < Kp; kt += BK) {
        if constexpr (ABF16) {
            const unsigned short* A = (const unsigned short*)Av;
#pragma unroll
            for (int i = 0; i < BM / 64; ++i) {
                int idx = i * 256 + t;
                int r = idx >> 2, kc = (idx & 3) * 8;
                int gr = row0 + r;
                s16x8 v = {};
                if (gr < M) v = *(const s16x8*)(A + (size_t)gr * lda + kt + kc);
                *(s16x8*)&As[r * LDK + kc] = v;
            }
        } else {
            const float* A = (const float*)Av;
            bool kfull = (kt + BK <= Kreal);
#pragma unroll
            for (int i = 0; i < BM / 32; ++i) {
                int idx = i * 256 + t;
                int r = idx >> 3, kc = (idx & 7) * 4;
                int gr = row0 + r;
                float v0 = 0.f, v1 = 0.f, v2 = 0.f, v3 = 0.f;
                if (gr < M) {
                    const float* p = A + (size_t)gr * lda + kt + kc;
                    if (kfull) {
                        float2 a = *(const float2*)p;
                        float2 b = *(const float2*)(p + 2);
                        v0 = a.x; v1 = a.y; v2 = b.x; v3 = b.y;
                    } else {
                        int kg = kt + kc;
                        if (kg + 0 < Kreal) v0 = p[0];
                        if (kg + 1 < Kreal) v1 = p[1];
                        if (kg + 2 < Kreal) v2 = p[2];
                        if (kg + 3 < Kreal) v3 = p[3];
                    }
                }
                ushort4 o;
                o.x = f2bf(v0); o.y = f2bf(v1); o.z = f2bf(v2); o.w = f2bf(v3);
                *(ushort4*)&As[r * LDK + kc] = o;
            }
        }
#pragma unroll
        for (int i = 0; i < BN / 64; ++i) {
            int idx = i * 256 + t;
            int r = idx >> 2, kc = (idx & 3) * 8;
            s16x8 v = *(const s16x8*)(Bt + (size_t)(col0 + r) * Kp + kt + kc);
            *(s16x8*)&Bs[r * LDK + kc] = v;
        }
        __syncthreads();
        s16x8 af[MR], bfr[NR];
#pragma unroll
        for (int m = 0; m < MR; ++m)
            af[m] = *(const s16x8*)&As[(wr * WM + m * 16 + r16) * LDK + kb];
#pragma unroll
        for (int n = 0; n < NR; ++n)
            bfr[n] = *(const s16x8*)&Bs[(wc * WN + n * 16 + r16) * LDK + kb];
#pragma unroll
        for (int m = 0; m < MR; ++m)
#pragma unroll
            for (int n = 0; n < NR; ++n)
                acc[m][n] = __builtin_amdgcn_mfma_f32_16x16x32_bf16(af[m], bfr[n], acc[m][n], 0, 0, 0);
        __syncthreads();
    }
#pragma unroll
    for (int m = 0; m < MR; ++m) {
#pragma unroll
        for (int n = 0; n < NR; ++n) {
            int col = col0 + wc * WN + n * 16 + r16;
#pragma unroll
            for (int r = 0; r < 4; ++r) {
                int row = row0 + wr * WM + m * 16 + (lane >> 4) * 4 + r;
                if (row < M) {
                    float v = acc[m][n][r] + (bias ? bias[col] : 0.f);
                    if (relu) v = fmaxf(v, 0.f);
                    if (Cf) Cf[(size_t)row * ldc + col] = v;
                    if (Cb) Cb[(size_t)row * ldc + col] = f2bf(v);
                }
            }
        }
    }
}

// ---------------- gene pathway gather -> bf16 feat ----------------
__global__ __launch_bounds__(64) void gene_feat_kernel(
    const float* __restrict__ S, const int* __restrict__ ids,
    const int* __restrict__ gene_paths, const void* __restrict__ mask,
    const int* __restrict__ root, unsigned short* __restrict__ feat, const int* __restrict__ flag) {
    __shared__ float lds[28 * 64];
    int lane = threadIdx.x;
#pragma unroll
    for (int i = 0; i < 28; ++i) lds[i * 64 + lane] = 0.f;
    int gene = ids[blockIdx.x];
    int fl = *flag;
    const unsigned char* mb = (const unsigned char*)mask;
    const int* mi = (const int*)mask;
    const float* mf = (const float*)mask;
    for (int p = 0; p < 32; ++p) {
        int idx = gene * 32 + p;
        int m = (fl == 0) ? mi[idx] : (fl == 1) ? (int)mb[idx] : (mf[idx] != 0.f);
        if (!m) continue;
        int path = gene_paths[idx];
        int r = root[path];
        lds[r * 64 + lane] += S[(size_t)path * 64 + lane];
    }
    unsigned short* frow = feat + (size_t)blockIdx.x * 1792;
#pragma unroll
    for (int i = 0; i < 28; ++i) frow[i * 64 + lane] = f2bf(lds[i * 64 + lane]);
}

// ---------------- batchnorm ----------------
__global__ __launch_bounds__(256) void bn_stats_kernel(const float* __restrict__ X, int Mrows, int C,
                                                       float* __restrict__ mean, float* __restrict__ rstd) {
    int c = blockIdx.x;
    float s = 0.f, s2 = 0.f;
    for (int r = threadIdx.x; r < Mrows; r += 256) {
        float v = X[(size_t)r * C + c];
        s += v; s2 += v * v;
    }
    for (int off = 32; off; off >>= 1) { s += __shfl_down(s, off); s2 += __shfl_down(s2, off); }
    __shared__ float sh[2][4];
    int lane = threadIdx.x & 63, wv = threadIdx.x >> 6;
    if (lane == 0) { sh[0][wv] = s; sh[1][wv] = s2; }
    __syncthreads();
    if (threadIdx.x == 0) {
        float ts = 0.f, ts2 = 0.f;
        for (int i = 0; i < 4; ++i) { ts += sh[0][i]; ts2 += sh[1][i]; }
        float mu = ts / Mrows;
        float var = ts2 / Mrows - mu * mu;
        mean[c] = mu;
        rstd[c] = rsqrtf(var + 1e-5f);
    }
}

__global__ void bn_apply_kernel(const float* __restrict__ X, unsigned short* __restrict__ Y,
                                int Mrows, int C, int ldY, int colOff,
                                const float* __restrict__ g, const float* __restrict__ b,
                                const float* __restrict__ mean, const float* __restrict__ rstd, int relu) {
    long long idx = (long long)blockIdx.x * 256 + threadIdx.x;
    if (idx >= (long long)Mrows * C) return;
    int r = (int)(idx / C), c = (int)(idx % C);
    float v = (X[idx] - mean[c]) * rstd[c] * g[c] + b[c];
    if (relu) v = fmaxf(v, 0.f);
    Y[(size_t)r * ldY + colOff + c] = f2bf(v);
}

// ---------------- final N=1 GEMV ----------------
__global__ __launch_bounds__(256) void gemv_out_kernel(const unsigned short* __restrict__ X,
                                                       const float* __restrict__ w,
                                                       const float* __restrict__ b, float* __restrict__ out,
                                                       int M, int K) {
    int gid = blockIdx.x * 256 + threadIdx.x;
    int row = gid >> 6, lane = gid & 63;
    if (row >= M) return;
    float sum = 0.f;
    for (int k = lane; k < K; k += 64) sum += b2f(X[(size_t)row * K + k]) * w[k];
    for (int off = 32; off; off >>= 1) sum += __shfl_down(sum, off);
    if (lane == 0) out[row] = sum + b[0];
}

// ---------------- launch ----------------
extern "C" void kernel_launch(void* const* d_in, const int* in_sizes, int n_in,
                              void* d_out, int out_size, void* d_ws, size_t ws_size,
                              hipStream_t stream) {
    const float* x[2] = {(const float*)d_in[0], (const float*)d_in[1]};
    const int* esrc = (const int*)d_in[2];
    const int* edst = (const int*)d_in[3];
    const float* ew = (const float*)d_in[4];
    const float* g_w1[2] = {(const float*)d_in[5], (const float*)d_in[9]};
    const float* g_b1[2] = {(const float*)d_in[6], (const float*)d_in[10]};
    const float* g_w2[2] = {(const float*)d_in[7], (const float*)d_in[11]};
    const float* g_b2[2] = {(const float*)d_in[8], (const float*)d_in[12]};
    const float* pl1_w = (const float*)d_in[13];
    const float* pl1_b = (const float*)d_in[14];
    const float* bn1_g = (const float*)d_in[15];
    const float* bn1_b = (const float*)d_in[16];
    const float* pl2_w = (const float*)d_in[17];
    const float* pl2_b = (const float*)d_in[18];
    const float* bn2_g = (const float*)d_in[19];
    const float* bn2_b = (const float*)d_in[20];
    const float* fc_w = (const float*)d_in[21];
    const float* fc_b = (const float*)d_in[22];
    const float* fc1_w = (const float*)d_in[23];
    const float* fc1_b = (const float*)d_in[24];
    const float* fc2_w = (const float*)d_in[25];
    const float* fc2_b = (const float*)d_in[26];
    const int* root = (const int*)d_in[27];
    const int* gene_paths = (const int*)d_in[28];
    const void* gmask = d_in[29];
    const int* ids[2] = {(const int*)d_in[30], (const int*)d_in[31]};

    const int P = in_sizes[27];   // 30000
    const int E = in_sizes[2];    // 480000
    const int B = in_sizes[30];   // 4096
    const int IN = 394, Kp1 = 416, H = 256, OUT = 64, GD = 128;

    char* ws = (char*)d_ws;
    size_t off = 0;
    auto alloc = [&](size_t bytes) -> char* {
        char* p = ws + off;
        off = (off + bytes + 255) & ~(size_t)255;
        return p;
    };
    int* flag = (int*)alloc(256);
    float* norm = (float*)alloc((size_t)P * 4);
    int* cnt = (int*)alloc((size_t)P * 4);
    int* fill = (int*)alloc((size_t)P * 4);
    int* rowstart = (int*)alloc((size_t)(P + 1) * 4);
    int* csrc = (int*)alloc((size_t)E * 4);
    float* coef = (float*)alloc((size_t)E * 4);
    unsigned short* W1t = (unsigned short*)alloc((size_t)H * Kp1 * 2);
    unsigned short* W2t = (unsigned short*)alloc((size_t)OUT * H * 2);
    unsigned short* pl1t = (unsigned short*)alloc((size_t)256 * 1792 * 2);
    unsigned short* pl2t = (unsigned short*)alloc((size_t)GD * 256 * 2);
    unsigned short* fct = (unsigned short*)alloc((size_t)256 * 256 * 2);
    unsigned short* fc1t = (unsigned short*)alloc((size_t)GD * 256 * 2);
    float* bn_mean = (float*)alloc(256 * 4);
    float* bn_rstd = (float*)alloc(256 * 4);
    unsigned short* Hb = (unsigned short*)alloc((size_t)P * H * 2);   // x@W1 out / h1@W2 out / feat
    unsigned short* h1 = (unsigned short*)alloc((size_t)P * H * 2);
    float* s = (float*)alloc((size_t)P * OUT * 4);
    float* z1 = (float*)alloc((size_t)B * 256 * 4);
    unsigned short* z1b = (unsigned short*)alloc((size_t)B * 256 * 2);
    float* z2 = (float*)alloc((size_t)B * GD * 4);
    unsigned short* fuse = (unsigned short*)alloc((size_t)B * 256 * 2);
    unsigned short* t1 = (unsigned short*)alloc((size_t)B * 256 * 2);
    unsigned short* t2 = (unsigned short*)alloc((size_t)B * GD * 2);
    (void)ws_size; (void)n_in; (void)out_size;

    detect_mask_kernel<<<1, 256, 0, stream>>>((const unsigned char*)gmask, 4096, flag);

    // ---- CSR build (edges shared by both graphs) ----
    zero_f_kernel<<<(P + 255) / 256, 256, 0, stream>>>(norm, P);
    zero_i_kernel<<<(P + 255) / 256, 256, 0, stream>>>(cnt, P);
    zero_i_kernel<<<(P + 255) / 256, 256, 0, stream>>>(fill, P);
    deg_cnt_kernel<<<(E + 255) / 256, 256, 0, stream>>>(edst, ew, norm, cnt, E);
    norm_kernel<<<(P + 255) / 256, 256, 0, stream>>>(norm, P);
    scan_kernel<<<1, 1024, 0, stream>>>(cnt, rowstart, P);
    fill_kernel<<<(E + 255) / 256, 256, 0, stream>>>(esrc, edst, ew, norm, rowstart, fill, csrc, coef, E);

    // ---- GCN for both graphs ----
    for (int g = 0; g < 2; ++g) {
        transpose_bf16_kernel<<<(H * Kp1 + 255) / 256, 256, 0, stream>>>(g_w1[g], W1t, IN, H, Kp1);
        transpose_bf16_kernel<<<(OUT * H + 255) / 256, 256, 0, stream>>>(g_w2[g], W2t, H, OUT, H);
        mfma_gemm_kernel<128, 128, 64, 64, false><<<dim3(H / 128, (P + 127) / 128), 256, 0, stream>>>(
            x[g], W1t, nullptr, nullptr, Hb, P, H, IN, Kp1, IN, H, 0);
        conv1_agg_kernel<<<P, 256, 0, stream>>>(Hb, norm, rowstart, csrc, coef, g_b1[g], h1, P);
        mfma_gemm_kernel<128, 64, 32, 64, true><<<dim3(1, (P + 127) / 128), 256, 0, stream>>>(
            h1, W2t, nullptr, nullptr, Hb, P, OUT, H, H, H, OUT, 0);
        conv2_agg_kernel<<<(P + 3) / 4, 256, 0, stream>>>(Hb, norm, rowstart, csrc, coef, g_b2[g], s, P, g);
    }

    // ---- fuse weights ----
    transpose_bf16_kernel<<<(256 * 1792 + 255) / 256, 256, 0, stream>>>(pl1_w, pl1t, 1792, 256, 1792);
    transpose_bf16_kernel<<<(GD * 256 + 255) / 256, 256, 0, stream>>>(pl2_w, pl2t, 256, GD, 256);
    transpose_bf16_kernel<<<(256 * 256 + 255) / 256, 256, 0, stream>>>(fc_w, fct, 256, 256, 256);
    transpose_bf16_kernel<<<(GD * 256 + 255) / 256, 256, 0, stream>>>(fc1_w, fc1t, 256, GD, 256);

    unsigned short* featb = Hb;  // alias: Hb dead after GCN, 15.4MB >= 14.7MB
    for (int side = 0; side < 2; ++side) {
        gene_feat_kernel<<<B, 64, 0, stream>>>(s, ids[side], gene_paths, gmask, root, featb, flag);
        mfma_gemm_kernel<64, 64, 32, 32, true><<<dim3(256 / 64, B / 64), 256, 0, stream>>>(
            featb, pl1t, pl1_b, z1, nullptr, B, 256, 1792, 1792, 1792, 256, 0);
        bn_stats_kernel<<<256, 256, 0, stream>>>(z1, B, 256, bn_mean, bn_rstd);
        bn_apply_kernel<<<(B * 256 + 255) / 256, 256, 0, stream>>>(z1, z1b, B, 256, 256, 0,
                                                                   bn1_g, bn1_b, bn_mean, bn_rstd, 1);
        mfma_gemm_kernel<64, 64, 32, 32, true><<<dim3(GD / 64, B / 64), 256, 0, stream>>>(
            z1b, pl2t, pl2_b, z2, nullptr, B, GD, 256, 256, 256, GD, 0);
        bn_stats_kernel<<<GD, 256, 0, stream>>>(z2, B, GD, bn_mean, bn_rstd);
        bn_apply_kernel<<<(B * GD + 255) / 256, 256, 0, stream>>>(z2, fuse, B, GD, 2 * GD, side * GD,
                                                                  bn2_g, bn2_b, bn_mean, bn_rstd, 0);
    }

    // ---- final MLP ----
    mfma_gemm_kernel<64, 64, 32, 32, true><<<dim3(256 / 64, B / 64), 256, 0, stream>>>(
        fuse, fct, fc_b, nullptr, t1, B, 256, 256, 256, 256, 256, 1);
    mfma_gemm_kernel<64, 64, 32, 32, true><<<dim3(GD / 64, B / 64), 256, 0, stream>>>(
        t1, fc1t, fc1_b, nullptr, t2, B, GD, 256, 256, 256, GD, 1);
    gemv_out_kernel<<<(B * 64 + 255) / 256, 256, 0, stream>>>(t2, fc2_w, fc2_b, (float*)d_out, B, GD);
}

// Round 3
// 432.985 us; speedup vs baseline: 5.2702x; 1.6958x over previous
//
#include <hip/hip_runtime.h>
#include <cstdint>

typedef __attribute__((ext_vector_type(4))) float f32x4;
typedef __attribute__((ext_vector_type(8))) short s16x8;

__device__ inline unsigned short f2bf(float f) {
    unsigned u = __float_as_uint(f);
    unsigned r = (u + 0x7FFFu + ((u >> 16) & 1u)) >> 16;
    return (unsigned short)r;
}
__device__ inline float b2f(unsigned short h) {
    return __uint_as_float(((unsigned)h) << 16);
}

// ---------------- utility ----------------
__global__ void zero_f_kernel(float* __restrict__ p, long long n) {
    long long i = (long long)blockIdx.x * 256 + threadIdx.x;
    if (i < n) p[i] = 0.f;
}

// Classify gene_paths_mask storage: 0 = int32 words (0/1), 1 = bool bytes, 2 = float32 (0/1.0)
__global__ void detect_mask_kernel(const unsigned char* __restrict__ m, int nbytes, int* __restrict__ flag) {
    __shared__ int isByte, isFloat;
    if (threadIdx.x == 0) { isByte = 0; isFloat = 0; }
    __syncthreads();
    const unsigned* w = (const unsigned*)m;
    for (int i = threadIdx.x; i < nbytes / 4; i += blockDim.x) {
        unsigned v = w[i];
        if (v == 0u || v == 1u) continue;
        if (v == 0x3f800000u) isFloat = 1; else isByte = 1;
    }
    __syncthreads();
    if (threadIdx.x == 0) *flag = isFloat ? 2 : (isByte ? 1 : 0);
}

// ---------------- CSR build ----------------
__global__ void deg_cnt_kernel(const int* __restrict__ dst, const float* __restrict__ ew,
                               float* __restrict__ degw, int* __restrict__ cnt, int E) {
    int e = blockIdx.x * 256 + threadIdx.x;
    if (e >= E) return;
    int d = dst[e];
    unsafeAtomicAdd(&degw[d], ew[e]);
    atomicAdd(&cnt[d], 1);
}

__global__ void norm_kernel(float* __restrict__ degw, int P) {
    int i = blockIdx.x * 256 + threadIdx.x;
    if (i < P) degw[i] = rsqrtf(degw[i] + 1.0f);
}

// single-block scan, shfl-based (3 barriers per 1024-tile)
__global__ __launch_bounds__(1024) void scan_kernel(const int* __restrict__ cnt,
                                                    int* __restrict__ rowstart, int P) {
    __shared__ int wsum[16];
    __shared__ int carry;
    int t = threadIdx.x, lane = t & 63, w = t >> 6;
    if (t == 0) { carry = 0; rowstart[0] = 0; }
    __syncthreads();
    for (int base = 0; base < P; base += 1024) {
        int v = (base + t < P) ? cnt[base + t] : 0;
        int x = v;
#pragma unroll
        for (int off = 1; off < 64; off <<= 1) {
            int y = __shfl_up(x, off);
            if (lane >= off) x += y;
        }
        if (lane == 63) wsum[w] = x;
        __syncthreads();
        if (w == 0) {
            int xs = (lane < 16) ? wsum[lane] : 0;
#pragma unroll
            for (int off = 1; off < 16; off <<= 1) {
                int y = __shfl_up(xs, off);
                if (lane >= off) xs += y;
            }
            if (lane < 16) wsum[lane] = xs;
        }
        __syncthreads();
        int wbase = (w == 0) ? 0 : wsum[w - 1];
        int inc = carry + wbase + x;
        if (base + t < P) rowstart[base + t + 1] = inc;
        __syncthreads();
        if (t == 1023) carry = inc;
        __syncthreads();
    }
}

__global__ void fill_kernel(const int* __restrict__ src, const int* __restrict__ dst,
                            const float* __restrict__ ew, const float* __restrict__ norm,
                            const int* __restrict__ rowstart, int* __restrict__ fill,
                            int* __restrict__ csrc, float* __restrict__ coef, int E) {
    int e = blockIdx.x * 256 + threadIdx.x;
    if (e >= E) return;
    int d = dst[e], sI = src[e];
    int pos = rowstart[d] + atomicAdd(&fill[d], 1);
    csrc[pos] = sI;
    coef[pos] = ew[e] * norm[sI] * norm[d];
}

// ---------------- conv1 aggregation: wave per node, both graphs via blockIdx.y ----------------
// out[z][i][f] = relu( H[z][i][f]*nn^2 + bias_z[f] + sum_e H[z][src][f]*coef )
__global__ __launch_bounds__(256) void conv1_agg_kernel(
    const unsigned short* __restrict__ Hb, const float* __restrict__ norm,
    const int* __restrict__ rowstart, const int* __restrict__ csrc, const float* __restrict__ coef,
    const float* __restrict__ b0, const float* __restrict__ b1,
    unsigned short* __restrict__ outb, int P) {
    int node = blockIdx.x * 4 + (threadIdx.x >> 6);
    if (node >= P) return;
    int z = blockIdx.y;
    const unsigned short* H = Hb + (size_t)z * P * 256;
    unsigned short* out = outb + (size_t)z * P * 256;
    const float* bias = z ? b1 : b0;
    int lane = threadIdx.x & 63;
    int f4 = lane * 4;
    float nn = norm[node];
    ushort4 hv = *(const ushort4*)(H + (size_t)node * 256 + f4);
    float a0 = b2f(hv.x) * nn * nn, a1 = b2f(hv.y) * nn * nn;
    float a2 = b2f(hv.z) * nn * nn, a3 = b2f(hv.w) * nn * nn;
    int s0 = rowstart[node], s1 = rowstart[node + 1];
    int p = s0;
    for (; p + 4 <= s1; p += 4) {
        int i0 = csrc[p], i1 = csrc[p + 1], i2 = csrc[p + 2], i3 = csrc[p + 3];
        float c0 = coef[p], c1 = coef[p + 1], c2 = coef[p + 2], c3 = coef[p + 3];
        ushort4 v0 = *(const ushort4*)(H + (size_t)i0 * 256 + f4);
        ushort4 v1 = *(const ushort4*)(H + (size_t)i1 * 256 + f4);
        ushort4 v2 = *(const ushort4*)(H + (size_t)i2 * 256 + f4);
        ushort4 v3 = *(const ushort4*)(H + (size_t)i3 * 256 + f4);
        a0 += b2f(v0.x) * c0 + b2f(v1.x) * c1 + b2f(v2.x) * c2 + b2f(v3.x) * c3;
        a1 += b2f(v0.y) * c0 + b2f(v1.y) * c1 + b2f(v2.y) * c2 + b2f(v3.y) * c3;
        a2 += b2f(v0.z) * c0 + b2f(v1.z) * c1 + b2f(v2.z) * c2 + b2f(v3.z) * c3;
        a3 += b2f(v0.w) * c0 + b2f(v1.w) * c1 + b2f(v2.w) * c2 + b2f(v3.w) * c3;
    }
    for (; p < s1; ++p) {
        int i0 = csrc[p];
        float c0 = coef[p];
        ushort4 v0 = *(const ushort4*)(H + (size_t)i0 * 256 + f4);
        a0 += b2f(v0.x) * c0; a1 += b2f(v0.y) * c0; a2 += b2f(v0.z) * c0; a3 += b2f(v0.w) * c0;
    }
    float4 bv = *(const float4*)(bias + f4);
    ushort4 o;
    o.x = f2bf(fmaxf(a0 + bv.x, 0.f));
    o.y = f2bf(fmaxf(a1 + bv.y, 0.f));
    o.z = f2bf(fmaxf(a2 + bv.z, 0.f));
    o.w = f2bf(fmaxf(a3 + bv.w, 0.f));
    *(ushort4*)(out + (size_t)node * 256 + f4) = o;
}

// ---------------- conv2 aggregation fused over both graphs: s = agg(H0)+agg(H1) ----------------
__global__ __launch_bounds__(256) void conv2_agg_kernel(
    const unsigned short* __restrict__ H2, const float* __restrict__ norm,
    const int* __restrict__ rowstart, const int* __restrict__ csrc, const float* __restrict__ coef,
    const float* __restrict__ b0, const float* __restrict__ b1,
    float* __restrict__ s, int P) {
    int node = blockIdx.x * 4 + (threadIdx.x >> 6);
    if (node >= P) return;
    int lane = threadIdx.x & 63;
    const unsigned short* Ha = H2;
    const unsigned short* Hc = H2 + (size_t)P * 64;
    float nn = norm[node];
    float acc = (b2f(Ha[(size_t)node * 64 + lane]) + b2f(Hc[(size_t)node * 64 + lane])) * nn * nn;
    int s0 = rowstart[node], s1 = rowstart[node + 1];
    int p = s0;
    for (; p + 4 <= s1; p += 4) {
        int i0 = csrc[p], i1 = csrc[p + 1], i2 = csrc[p + 2], i3 = csrc[p + 3];
        float c0 = coef[p], c1 = coef[p + 1], c2 = coef[p + 2], c3 = coef[p + 3];
        float u0 = b2f(Ha[(size_t)i0 * 64 + lane]), w0 = b2f(Hc[(size_t)i0 * 64 + lane]);
        float u1 = b2f(Ha[(size_t)i1 * 64 + lane]), w1 = b2f(Hc[(size_t)i1 * 64 + lane]);
        float u2 = b2f(Ha[(size_t)i2 * 64 + lane]), w2 = b2f(Hc[(size_t)i2 * 64 + lane]);
        float u3 = b2f(Ha[(size_t)i3 * 64 + lane]), w3 = b2f(Hc[(size_t)i3 * 64 + lane]);
        acc += (u0 + w0) * c0 + (u1 + w1) * c1 + (u2 + w2) * c2 + (u3 + w3) * c3;
    }
    for (; p < s1; ++p) {
        int i0 = csrc[p];
        acc += (b2f(Ha[(size_t)i0 * 64 + lane]) + b2f(Hc[(size_t)i0 * 64 + lane])) * coef[p];
    }
    s[(size_t)node * 64 + lane] = acc + b0[lane] + b1[lane];
}

// ---------------- multi-transpose: 8 descriptors, blockIdx.y selects ----------------
struct TD { const float* in; unsigned short* out; int K, N, Kp; };
__global__ void multi_transpose_kernel(TD d0, TD d1, TD d2, TD d3, TD d4, TD d5, TD d6, TD d7) {
    TD d = d0;
    int y = blockIdx.y;
    if (y == 1) d = d1; else if (y == 2) d = d2; else if (y == 3) d = d3;
    else if (y == 4) d = d4; else if (y == 5) d = d5; else if (y == 6) d = d6; else if (y == 7) d = d7;
    int idx = blockIdx.x * 256 + threadIdx.x;
    int total = d.N * d.Kp;
    if (idx >= total) return;
    int n = idx / d.Kp, k = idx - n * d.Kp;
    d.out[idx] = (k < d.K) ? f2bf(d.in[(size_t)k * d.N + n]) : (unsigned short)0;
}

// ---------------- bf16 MFMA GEMM, 2-slot batched via blockIdx.z ----------------
struct G2 {
    const void* A[2]; const unsigned short* Bt[2]; const float* bias[2];
    float* Cf[2]; unsigned short* Cb[2];
};
template<int BM, int BN, int WM, int WN, bool ABF16>
__global__ __launch_bounds__(256) void mfma_gemm_kernel(
    G2 g, int M, int N, int Kreal, int Kp, int lda, int ldc, int relu) {
    const int z = blockIdx.z;
    const void* Av = z ? g.A[1] : g.A[0];
    const unsigned short* Bt = z ? g.Bt[1] : g.Bt[0];
    const float* bias = z ? g.bias[1] : g.bias[0];
    float* Cf = z ? g.Cf[1] : g.Cf[0];
    unsigned short* Cb = z ? g.Cb[1] : g.Cb[0];

    constexpr int BK = 32, LDK = BK + 8;
    __shared__ __align__(16) unsigned short As[BM * LDK];
    __shared__ __align__(16) unsigned short Bs[BN * LDK];
    const int t = threadIdx.x;
    const int lane = t & 63, wid = t >> 6;
    constexpr int NWC = BN / WN;
    const int wr = wid / NWC, wc = wid % NWC;
    constexpr int MR = WM / 16, NR = WN / 16;
    const int row0 = blockIdx.y * BM, col0 = blockIdx.x * BN;
    f32x4 acc[MR][NR] = {};
    const int r16 = lane & 15, kb = (lane >> 4) * 8;

    for (int kt = 0; kt < Kp; kt += BK) {
        if constexpr (ABF16) {
            const unsigned short* A = (const unsigned short*)Av;
#pragma unroll
            for (int i = 0; i < BM / 64; ++i) {
                int idx = i * 256 + t;
                int r = idx >> 2, kc = (idx & 3) * 8;
                int gr = row0 + r;
                s16x8 v = {};
                if (gr < M) v = *(const s16x8*)(A + (size_t)gr * lda + kt + kc);
                *(s16x8*)&As[r * LDK + kc] = v;
            }
        } else {
            const float* A = (const float*)Av;
            bool kfull = (kt + BK <= Kreal);
#pragma unroll
            for (int i = 0; i < BM / 32; ++i) {
                int idx = i * 256 + t;
                int r = idx >> 3, kc = (idx & 7) * 4;
                int gr = row0 + r;
                float v0 = 0.f, v1 = 0.f, v2 = 0.f, v3 = 0.f;
                if (gr < M) {
                    const float* p = A + (size_t)gr * lda + kt + kc;
                    if (kfull) {
                        float2 a = *(const float2*)p;
                        float2 b = *(const float2*)(p + 2);
                        v0 = a.x; v1 = a.y; v2 = b.x; v3 = b.y;
                    } else {
                        int kg = kt + kc;
                        if (kg + 0 < Kreal) v0 = p[0];
                        if (kg + 1 < Kreal) v1 = p[1];
                        if (kg + 2 < Kreal) v2 = p[2];
                        if (kg + 3 < Kreal) v3 = p[3];
                    }
                }
                ushort4 o;
                o.x = f2bf(v0); o.y = f2bf(v1); o.z = f2bf(v2); o.w = f2bf(v3);
                *(ushort4*)&As[r * LDK + kc] = o;
            }
        }
#pragma unroll
        for (int i = 0; i < BN / 64; ++i) {
            int idx = i * 256 + t;
            int r = idx >> 2, kc = (idx & 3) * 8;
            s16x8 v = *(const s16x8*)(Bt + (size_t)(col0 + r) * Kp + kt + kc);
            *(s16x8*)&Bs[r * LDK + kc] = v;
        }
        __syncthreads();
        s16x8 af[MR], bfr[NR];
#pragma unroll
        for (int m = 0; m < MR; ++m)
            af[m] = *(const s16x8*)&As[(wr * WM + m * 16 + r16) * LDK + kb];
#pragma unroll
        for (int n = 0; n < NR; ++n)
            bfr[n] = *(const s16x8*)&Bs[(wc * WN + n * 16 + r16) * LDK + kb];
#pragma unroll
        for (int m = 0; m < MR; ++m)
#pragma unroll
            for (int n = 0; n < NR; ++n)
                acc[m][n] = __builtin_amdgcn_mfma_f32_16x16x32_bf16(af[m], bfr[n], acc[m][n], 0, 0, 0);
        __syncthreads();
    }
#pragma unroll
    for (int m = 0; m < MR; ++m) {
#pragma unroll
        for (int n = 0; n < NR; ++n) {
            int col = col0 + wc * WN + n * 16 + r16;
#pragma unroll
            for (int r = 0; r < 4; ++r) {
                int row = row0 + wr * WM + m * 16 + (lane >> 4) * 4 + r;
                if (row < M) {
                    float v = acc[m][n][r] + (bias ? bias[col] : 0.f);
                    if (relu) v = fmaxf(v, 0.f);
                    if (Cf) Cf[(size_t)row * ldc + col] = v;
                    if (Cb) Cb[(size_t)row * ldc + col] = f2bf(v);
                }
            }
        }
    }
}

// ---------------- gene pathway gather -> bf16 feat, both sides via blockIdx.y ----------------
__global__ __launch_bounds__(64) void gene_feat_kernel(
    const float* __restrict__ S, const int* __restrict__ head, const int* __restrict__ tail,
    const int* __restrict__ gene_paths, const void* __restrict__ mask,
    const int* __restrict__ root, unsigned short* __restrict__ feat, const int* __restrict__ flag,
    int B) {
    __shared__ float lds[28 * 64];
    int lane = threadIdx.x;
#pragma unroll
    for (int i = 0; i < 28; ++i) lds[i * 64 + lane] = 0.f;
    int side = blockIdx.y;
    const int* ids = side ? tail : head;
    int gene = ids[blockIdx.x];
    int fl = *flag;
    const unsigned char* mb = (const unsigned char*)mask;
    const int* mi = (const int*)mask;
    const float* mf = (const float*)mask;
    for (int p = 0; p < 32; ++p) {
        int idx = gene * 32 + p;
        int m = (fl == 0) ? mi[idx] : (fl == 1) ? (int)mb[idx] : (mf[idx] != 0.f);
        if (!m) continue;
        int path = gene_paths[idx];
        int r = root[path];
        lds[r * 64 + lane] += S[(size_t)path * 64 + lane];
    }
    unsigned short* frow = feat + ((size_t)side * B + blockIdx.x) * 1792;
#pragma unroll
    for (int i = 0; i < 28; ++i) frow[i * 64 + lane] = f2bf(lds[i * 64 + lane]);
}

// ---------------- batchnorm (sides batched via blockIdx.y) ----------------
__global__ __launch_bounds__(256) void bn_stats_kernel(const float* __restrict__ X, int Mrows, int C,
                                                       size_t sideStride,
                                                       float* __restrict__ mean, float* __restrict__ rstd) {
    int c = blockIdx.x, side = blockIdx.y;
    const float* Xs = X + (size_t)side * sideStride;
    float s = 0.f, s2 = 0.f;
    for (int r = threadIdx.x; r < Mrows; r += 256) {
        float v = Xs[(size_t)r * C + c];
        s += v; s2 += v * v;
    }
    for (int off = 32; off; off >>= 1) { s += __shfl_down(s, off); s2 += __shfl_down(s2, off); }
    __shared__ float sh[2][4];
    int lane = threadIdx.x & 63, wv = threadIdx.x >> 6;
    if (lane == 0) { sh[0][wv] = s; sh[1][wv] = s2; }
    __syncthreads();
    if (threadIdx.x == 0) {
        float ts = 0.f, ts2 = 0.f;
        for (int i = 0; i < 4; ++i) { ts += sh[0][i]; ts2 += sh[1][i]; }
        float mu = ts / Mrows;
        float var = ts2 / Mrows - mu * mu;
        mean[side * C + c] = mu;
        rstd[side * C + c] = rsqrtf(var + 1e-5f);
    }
}

__global__ void bn_apply_kernel(const float* __restrict__ X, unsigned short* __restrict__ Y,
                                int Mrows, int C, size_t sideStrideX, size_t sideStrideY,
                                int ldY, int colPerSide,
                                const float* __restrict__ g, const float* __restrict__ b,
                                const float* __restrict__ mean, const float* __restrict__ rstd, int relu) {
    long long idx = (long long)blockIdx.x * 256 + threadIdx.x;
    if (idx >= (long long)Mrows * C) return;
    int side = blockIdx.y;
    int r = (int)(idx / C), c = (int)(idx % C);
    float v = (X[(size_t)side * sideStrideX + idx] - mean[side * C + c]) * rstd[side * C + c] * g[c] + b[c];
    if (relu) v = fmaxf(v, 0.f);
    Y[(size_t)side * sideStrideY + (size_t)r * ldY + side * colPerSide + c] = f2bf(v);
}

// ---------------- final N=1 GEMV ----------------
__global__ __launch_bounds__(256) void gemv_out_kernel(const unsigned short* __restrict__ X,
                                                       const float* __restrict__ w,
                                                       const float* __restrict__ b, float* __restrict__ out,
                                                       int M, int K) {
    int gid = blockIdx.x * 256 + threadIdx.x;
    int row = gid >> 6, lane = gid & 63;
    if (row >= M) return;
    float sum = 0.f;
    for (int k = lane; k < K; k += 64) sum += b2f(X[(size_t)row * K + k]) * w[k];
    for (int off = 32; off; off >>= 1) sum += __shfl_down(sum, off);
    if (lane == 0) out[row] = sum + b[0];
}

// ---------------- launch ----------------
extern "C" void kernel_launch(void* const* d_in, const int* in_sizes, int n_in,
                              void* d_out, int out_size, void* d_ws, size_t ws_size,
                              hipStream_t stream) {
    const float* x[2] = {(const float*)d_in[0], (const float*)d_in[1]};
    const int* esrc = (const int*)d_in[2];
    const int* edst = (const int*)d_in[3];
    const float* ew = (const float*)d_in[4];
    const float* g_w1[2] = {(const float*)d_in[5], (const float*)d_in[9]};
    const float* g_b1[2] = {(const float*)d_in[6], (const float*)d_in[10]};
    const float* g_w2[2] = {(const float*)d_in[7], (const float*)d_in[11]};
    const float* g_b2[2] = {(const float*)d_in[8], (const float*)d_in[12]};
    const float* pl1_w = (const float*)d_in[13];
    const float* pl1_b = (const float*)d_in[14];
    const float* bn1_g = (const float*)d_in[15];
    const float* bn1_b = (const float*)d_in[16];
    const float* pl2_w = (const float*)d_in[17];
    const float* pl2_b = (const float*)d_in[18];
    const float* bn2_g = (const float*)d_in[19];
    const float* bn2_b = (const float*)d_in[20];
    const float* fc_w = (const float*)d_in[21];
    const float* fc_b = (const float*)d_in[22];
    const float* fc1_w = (const float*)d_in[23];
    const float* fc1_b = (const float*)d_in[24];
    const float* fc2_w = (const float*)d_in[25];
    const float* fc2_b = (const float*)d_in[26];
    const int* root = (const int*)d_in[27];
    const int* gene_paths = (const int*)d_in[28];
    const void* gmask = d_in[29];
    const int* head = (const int*)d_in[30];
    const int* tail = (const int*)d_in[31];

    const int P = in_sizes[27];   // 30000
    const int E = in_sizes[2];    // 480000
    const int B = in_sizes[30];   // 4096
    const int IN = 394, Kp1 = 416, H = 256, OUT = 64, GD = 128;

    char* ws = (char*)d_ws;
    size_t off = 0;
    auto alloc = [&](size_t bytes) -> char* {
        char* p = ws + off;
        off = (off + bytes + 255) & ~(size_t)255;
        return p;
    };
    int* flag = (int*)alloc(256);
    float* norm = (float*)alloc((size_t)P * 4);
    int* cnt = (int*)alloc((size_t)P * 4);
    int* fillp = (int*)alloc((size_t)P * 4);
    int* rowstart = (int*)alloc((size_t)(P + 1) * 4);
    int* csrc = (int*)alloc((size_t)E * 4);
    float* coef = (float*)alloc((size_t)E * 4);
    unsigned short* W1t = (unsigned short*)alloc((size_t)2 * H * Kp1 * 2);
    unsigned short* W2t = (unsigned short*)alloc((size_t)2 * OUT * H * 2);
    unsigned short* pl1t = (unsigned short*)alloc((size_t)256 * 1792 * 2);
    unsigned short* pl2t = (unsigned short*)alloc((size_t)GD * 256 * 2);
    unsigned short* fct = (unsigned short*)alloc((size_t)256 * 256 * 2);
    unsigned short* fc1t = (unsigned short*)alloc((size_t)GD * 256 * 2);
    float* bn_mean = (float*)alloc((size_t)2 * 256 * 4);
    float* bn_rstd = (float*)alloc((size_t)2 * 256 * 4);
    unsigned short* bufH = (unsigned short*)alloc((size_t)2 * P * H * 2);   // 30.7MB
    unsigned short* bufh1 = (unsigned short*)alloc((size_t)2 * P * H * 2);  // 30.7MB
    float* s = (float*)alloc((size_t)P * OUT * 4);                          // 7.7MB
    (void)ws_size; (void)n_in; (void)out_size;

    // aliases into dead regions:
    unsigned short* bufh2 = bufH;                        // [2][P][64] bf16 (GEMM2 out), 7.7MB
    unsigned short* feat = bufh1;                        // [2][B][1792] bf16, 29.4MB <= 30.7MB
    char* mlp = (char*)bufH;                             // MLP scratch after conv2 done
    float* z1 = (float*)mlp;                             // [2][B][256] f32   8.39MB
    unsigned short* z1b = (unsigned short*)(mlp + 8500000 - 8500000 % 256);  // keep simple below
    // carve MLP scratch with explicit offsets (256B aligned):
    size_t mo = 0;
    auto malloc2 = [&](size_t bytes) -> char* {
        char* p = mlp + mo;
        mo = (mo + bytes + 255) & ~(size_t)255;
        return p;
    };
    z1 = (float*)malloc2((size_t)2 * B * 256 * 4);
    z1b = (unsigned short*)malloc2((size_t)2 * B * 256 * 2);
    float* z2 = (float*)malloc2((size_t)2 * B * GD * 4);
    unsigned short* fuse = (unsigned short*)malloc2((size_t)B * 256 * 2);
    unsigned short* t1 = (unsigned short*)malloc2((size_t)B * 256 * 2);
    unsigned short* t2 = (unsigned short*)malloc2((size_t)B * GD * 2);

    detect_mask_kernel<<<1, 256, 0, stream>>>((const unsigned char*)gmask, 4096, flag);

    // ---- CSR build ----
    long long spanWords = ((char*)(fillp + P) - (char*)norm) / 4;
    zero_f_kernel<<<(int)((spanWords + 255) / 256), 256, 0, stream>>>(norm, spanWords);
    deg_cnt_kernel<<<(E + 255) / 256, 256, 0, stream>>>(edst, ew, norm, cnt, E);
    norm_kernel<<<(P + 255) / 256, 256, 0, stream>>>(norm, P);
    scan_kernel<<<1, 1024, 0, stream>>>(cnt, rowstart, P);
    fill_kernel<<<(E + 255) / 256, 256, 0, stream>>>(esrc, edst, ew, norm, rowstart, fillp, csrc, coef, E);

    // ---- all weight transposes in one launch ----
    {
        TD d0 = {g_w1[0], W1t, IN, H, Kp1};
        TD d1 = {g_w1[1], W1t + (size_t)H * Kp1, IN, H, Kp1};
        TD d2 = {g_w2[0], W2t, H, OUT, H};
        TD d3 = {g_w2[1], W2t + (size_t)OUT * H, H, OUT, H};
        TD d4 = {pl1_w, pl1t, 1792, 256, 1792};
        TD d5 = {pl2_w, pl2t, 256, GD, 256};
        TD d6 = {fc_w, fct, 256, 256, 256};
        TD d7 = {fc1_w, fc1t, 256, GD, 256};
        multi_transpose_kernel<<<dim3(1792, 8), 256, 0, stream>>>(d0, d1, d2, d3, d4, d5, d6, d7);
    }

    // ---- GCN both graphs, batched ----
    {
        G2 g = {{x[0], x[1]}, {W1t, W1t + (size_t)H * Kp1}, {nullptr, nullptr},
                {nullptr, nullptr}, {bufH, bufH + (size_t)P * H}};
        mfma_gemm_kernel<128, 128, 64, 64, false><<<dim3(H / 128, (P + 127) / 128, 2), 256, 0, stream>>>(
            g, P, H, IN, Kp1, IN, H, 0);
    }
    conv1_agg_kernel<<<dim3((P + 3) / 4, 2), 256, 0, stream>>>(bufH, norm, rowstart, csrc, coef,
                                                               g_b1[0], g_b1[1], bufh1, P);
    {
        G2 g = {{bufh1, bufh1 + (size_t)P * H}, {W2t, W2t + (size_t)OUT * H}, {nullptr, nullptr},
                {nullptr, nullptr}, {bufh2, bufh2 + (size_t)P * OUT}};
        mfma_gemm_kernel<128, 64, 32, 64, true><<<dim3(1, (P + 127) / 128, 2), 256, 0, stream>>>(
            g, P, OUT, H, H, H, OUT, 0);
    }
    conv2_agg_kernel<<<dim3((P + 3) / 4), 256, 0, stream>>>(bufh2, norm, rowstart, csrc, coef,
                                                            g_b2[0], g_b2[1], s, P);

    // ---- head/tail fuse paths, batched ----
    gene_feat_kernel<<<dim3(B, 2), 64, 0, stream>>>(s, head, tail, gene_paths, gmask, root, feat, flag, B);
    {
        G2 g = {{feat, feat + (size_t)B * 1792}, {pl1t, pl1t}, {pl1_b, pl1_b},
                {z1, z1 + (size_t)B * 256}, {nullptr, nullptr}};
        mfma_gemm_kernel<64, 64, 32, 32, true><<<dim3(256 / 64, B / 64, 2), 256, 0, stream>>>(
            g, B, 256, 1792, 1792, 1792, 256, 0);
    }
    bn_stats_kernel<<<dim3(256, 2), 256, 0, stream>>>(z1, B, 256, (size_t)B * 256, bn_mean, bn_rstd);
    bn_apply_kernel<<<dim3((B * 256 + 255) / 256, 2), 256, 0, stream>>>(
        z1, z1b, B, 256, (size_t)B * 256, (size_t)B * 256, 256, 0,
        bn1_g, bn1_b, bn_mean, bn_rstd, 1);
    {
        G2 g = {{z1b, z1b + (size_t)B * 256}, {pl2t, pl2t}, {pl2_b, pl2_b},
                {z2, z2 + (size_t)B * GD}, {nullptr, nullptr}};
        mfma_gemm_kernel<64, 64, 32, 32, true><<<dim3(GD / 64, B / 64, 2), 256, 0, stream>>>(
            g, B, GD, 256, 256, 256, GD, 0);
    }
    bn_stats_kernel<<<dim3(GD, 2), 256, 0, stream>>>(z2, B, GD, (size_t)B * GD, bn_mean, bn_rstd);
    bn_apply_kernel<<<dim3((B * GD + 255) / 256, 2), 256, 0, stream>>>(
        z2, fuse, B, GD, (size_t)B * GD, 0, 256, GD,
        bn2_g, bn2_b, bn_mean, bn_rstd, 0);

    // ---- final MLP ----
    {
        G2 g = {{fuse, fuse}, {fct, fct}, {fc_b, fc_b}, {nullptr, nullptr}, {t1, t1}};
        mfma_gemm_kernel<64, 64, 32, 32, true><<<dim3(256 / 64, B / 64, 1), 256, 0, stream>>>(
            g, B, 256, 256, 256, 256, 256, 1);
    }
    {
        G2 g = {{t1, t1}, {fc1t, fc1t}, {fc1_b, fc1_b}, {nullptr, nullptr}, {t2, t2}};
        mfma_gemm_kernel<64, 64, 32, 32, true><<<dim3(GD / 64, B / 64, 1), 256, 0, stream>>>(
            g, B, GD, 256, 256, 256, GD, 1);
    }
    gemv_out_kernel<<<(B * 64 + 255) / 256, 256, 0, stream>>>(t2, fc2_w, fc2_b, (float*)d_out, B, GD);
}